// Round 15
// baseline (1699.911 us; speedup 1.0000x reference)
//
#include <hip/hip_runtime.h>
#include <hip/hip_bf16.h>

#define NPT   16384
#define NQ    512
#define NS    32
#define BATCH 8
#define NCONS 248          // consumer blocks (persistent, grid-stride)
#define NPAIR 2048         // 4096 groups processed as 2048 pairs

typedef float f32x2 __attribute__((ext_vector_type(2)));

// ---------------------------------------------------------------------------
// DPP helper on a 64-bit value (two 32-bit halves), invalid lanes -> 0.
// Keys are (dist_bits<<32)|~idx, positive finite f64 patterns -> v_max_f64
// == exact u64 max (see prior rounds).
// ---------------------------------------------------------------------------
template <int CTRL>
__device__ inline double dpp_f64(double x)
{
    const unsigned long long u = (unsigned long long)__double_as_longlong(x);
    int lo = (int)(unsigned)u;
    int hi = (int)(unsigned)(u >> 32);
    lo = __builtin_amdgcn_update_dpp(0, lo, CTRL, 0xf, 0xf, true);
    hi = __builtin_amdgcn_update_dpp(0, hi, CTRL, 0xf, 0xf, true);
    return __longlong_as_double(
        (long long)(((unsigned long long)(unsigned)hi << 32) | (unsigned)lo));
}

// ---------------------------------------------------------------------------
// R8 mlp building blocks (math unchanged, bit-identical FMA order; compiled
// with default contraction exactly as in the passing R8/R12 builds).
// ---------------------------------------------------------------------------
template <int OP>
__device__ inline void mlp_layer(const float* __restrict__ inb,
                                 const float* __restrict__ wbuf,
                                 const float* __restrict__ scp,
                                 const float* __restrict__ bip,
                                 float* __restrict__ outb, int nchunk, int t)
{
    const int ko = t & 15;
    const int og = t >> 4;
    const int o0 = og * OP;
    float acc0[OP], acc1[OP];
#pragma unroll
    for (int j = 0; j < OP; ++j) { acc0[j] = 0.f; acc1[j] = 0.f; }

    for (int cc = 0; cc < nchunk; ++cc) {
        const int c = cc * 4;
        const float4 xa = *(const float4*)(inb + ko * 68 + c);
        const float4 xb = *(const float4*)(inb + (ko + 16) * 68 + c);
#pragma unroll
        for (int j = 0; j < OP; ++j) {
            const float4 w = *(const float4*)(wbuf + (o0 + j) * 68 + c);
            acc0[j] += xa.x * w.x + xa.y * w.y + xa.z * w.z + xa.w * w.w;
            acc1[j] += xb.x * w.x + xb.y * w.y + xb.z * w.z + xb.w * w.w;
        }
    }
#pragma unroll
    for (int j = 0; j < OP; ++j) {
        const float sv = scp[o0 + j], bv = bip[o0 + j];
        acc0[j] = fmaxf(acc0[j] * sv + bv, 0.f);
        acc1[j] = fmaxf(acc1[j] * sv + bv, 0.f);
    }
#pragma unroll
    for (int jb = 0; jb < OP; jb += 4) {
        *(float4*)(outb + ko * 68 + o0 + jb) =
            make_float4(acc0[jb], acc0[jb + 1], acc0[jb + 2], acc0[jb + 3]);
        *(float4*)(outb + (ko + 16) * 68 + o0 + jb) =
            make_float4(acc1[jb], acc1[jb + 1], acc1[jb + 2], acc1[jb + 3]);
    }
}

__device__ inline void mlp_layer2(const float* __restrict__ inb,
                                  const float* __restrict__ wbuf,
                                  const float* __restrict__ scp,
                                  const float* __restrict__ bip,
                                  float* __restrict__ out, int b, int s, int t)
{
    const int ko = t & 15;
    const int og = t >> 4;
    const int o0 = og * 8;
    float acc0[8], acc1[8];
#pragma unroll
    for (int j = 0; j < 8; ++j) { acc0[j] = 0.f; acc1[j] = 0.f; }

    for (int cc = 0; cc < 16; ++cc) {
        const int c = cc * 4;
        const float4 xa = *(const float4*)(inb + ko * 68 + c);
        const float4 xb = *(const float4*)(inb + (ko + 16) * 68 + c);
#pragma unroll
        for (int j = 0; j < 8; ++j) {
            const float4 w = *(const float4*)(wbuf + (o0 + j) * 68 + c);
            acc0[j] += xa.x * w.x + xa.y * w.y + xa.z * w.z + xa.w * w.w;
            acc1[j] += xb.x * w.x + xb.y * w.y + xb.z * w.z + xb.w * w.w;
        }
    }
    float v[8];
#pragma unroll
    for (int j = 0; j < 8; ++j) {
        const float sv = scp[o0 + j], bv = bip[o0 + j];
        const float h0 = fmaxf(acc0[j] * sv + bv, 0.f);
        const float h1 = fmaxf(acc1[j] * sv + bv, 0.f);
        v[j] = fmaxf(h0, h1);
    }
#pragma unroll
    for (int m = 1; m <= 8; m <<= 1) {
#pragma unroll
        for (int j = 0; j < 8; ++j) v[j] = fmaxf(v[j], __shfl_xor(v[j], m, 64));
    }
    if (ko == 0) {
#pragma unroll
        for (int j = 0; j < 8; ++j)
            out[((size_t)b * 128 + o0 + j) * NQ + s] = v[j];
    }
}

// ---------------------------------------------------------------------------
// ROUND-15 = ROUND-13 with the compile error fixed: '#pragma clang fp
// contract(off)' must be the FIRST statement of a compound statement; it now
// opens the producer's if-block (scoping contract-off to exactly the fps
// math, as in all passing rounds). R13's "container failure" was this
// compile error surfacing differently.
//
// Fused producer-consumer pipeline.
// Blocks 0..7: fps producers (exact R12 math; selection bit-identical).
//   new_xyz written via relaxed agent atomics; per-batch progress flag
//   (128B-strided) release-stored after each sample. Fire-and-forget:
//   NOTHING on the producer critical path waits. setprio(3) biases
//   producer waves if a consumer block shares the CU.
// Blocks 8..255: 248 persistent consumers, grid-stride over 2048 group-
//   PAIRS in s-major order (matches production order). Per pair: acquire-
//   spin on both flags -> bq (R8 math, wave 0 of each 256-thread half,
//   gidx in LDS) -> R8 mlp (shared weight staging by half 0; each half
//   computes its own group).
// Capacity: production 5.2 groups/us; consumers ~10 groups/us -> no
// backlog; expected total ~ fps(790) + one-pair tail.
// ---------------------------------------------------------------------------
__global__ __launch_bounds__(512)
void fused_kernel(const float* __restrict__ xyz, const float* __restrict__ feat,
                  float* __restrict__ new_xyz,
                  const float* __restrict__ w0, const float* __restrict__ g0,
                  const float* __restrict__ b0, const float* __restrict__ m0,
                  const float* __restrict__ v0,
                  const float* __restrict__ w1, const float* __restrict__ g1,
                  const float* __restrict__ b1, const float* __restrict__ m1,
                  const float* __restrict__ v1,
                  const float* __restrict__ w2, const float* __restrict__ g2,
                  const float* __restrict__ b2, const float* __restrict__ m2,
                  const float* __restrict__ v2,
                  float* __restrict__ out, unsigned* __restrict__ flags)
{
    __shared__ float wbuf[128 * 68];     // 34816 B
    __shared__ float bufA[2][32 * 68];   // 17408 B
    __shared__ float bufB[2][32 * 68];   // 17408 B
    __shared__ float sc[256], bi[256];   //  2048 B
    __shared__ int   gidxL[2][NS];       //   256 B
    __shared__ float qbuf[2][3];         //    24 B
    __shared__ unsigned long long red[2][8];  // 128 B  -> ~72 KB total

    const int t = threadIdx.x;

    if (blockIdx.x < BATCH) {
#pragma clang fp contract(off)
        // ================= producer: fps for batch b =================
        __builtin_amdgcn_s_setprio(3);
        const int b = blockIdx.x;
        const float* xb = xyz + (size_t)b * NPT * 3;

        f32x2 xr[16], yr[16], zr[16], dr[16];
        const float INF = __int_as_float(0x7f800000);
#pragma unroll
        for (int j = 0; j < 16; ++j) {
            const int p0 = (2 * j) * 512 + t;
            const int p1 = (2 * j + 1) * 512 + t;
            xr[j] = (f32x2){xb[p0 * 3 + 0], xb[p1 * 3 + 0]};
            yr[j] = (f32x2){xb[p0 * 3 + 1], xb[p1 * 3 + 1]};
            zr[j] = (f32x2){xb[p0 * 3 + 2], xb[p1 * 3 + 2]};
            dr[j] = (f32x2){INF, INF};
        }

        float px = xb[0], py = xb[1], pz = xb[2];

        for (int s = 0; s < NQ; ++s) {
            if (t == 0) {
                unsigned* o = (unsigned*)(new_xyz + ((size_t)b * NQ + s) * 3);
                __hip_atomic_store(o + 0, __float_as_uint(px),
                                   __ATOMIC_RELAXED, __HIP_MEMORY_SCOPE_AGENT);
                __hip_atomic_store(o + 1, __float_as_uint(py),
                                   __ATOMIC_RELAXED, __HIP_MEMORY_SCOPE_AGENT);
                __hip_atomic_store(o + 2, __float_as_uint(pz),
                                   __ATOMIC_RELAXED, __HIP_MEMORY_SCOPE_AGENT);
                __hip_atomic_store(&flags[b * 32], (unsigned)(s + 1),
                                   __ATOMIC_RELEASE, __HIP_MEMORY_SCOPE_AGENT);
            }
            if (s == NQ - 1) break;

            const f32x2 pxv = {px, px}, pyv = {py, py}, pzv = {pz, pz};
            float dmax = -1.0f;
            int   bi_  = 0;
#pragma unroll
            for (int j = 0; j < 16; ++j) {
                const f32x2 dx = xr[j] - pxv;
                const f32x2 dy = yr[j] - pyv;
                const f32x2 dz = zr[j] - pzv;
                f32x2 d = (dx * dx + dy * dy);       // rn mul/add, no fma
                d = d + dz * dz;
                const f32x2 dn = __builtin_elementwise_min(dr[j], d);
                dr[j] = dn;
                const float ds = (dn.x >= dn.y) ? dn.x : dn.y;
                const int   is = (dn.x >= dn.y) ? (2 * j) : (2 * j + 1);
                if (ds > dmax) { dmax = ds; bi_ = is; }
            }

            const unsigned pidx = (unsigned)(bi_ * 512 + t);
            double kd = __longlong_as_double((long long)(
                ((unsigned long long)__float_as_uint(dmax) << 32) |
                (unsigned)(~pidx)));

            kd = fmax(kd, dpp_f64<0x111>(kd));
            kd = fmax(kd, dpp_f64<0x112>(kd));
            kd = fmax(kd, dpp_f64<0x114>(kd));
            kd = fmax(kd, dpp_f64<0x118>(kd));
            kd = fmax(kd, dpp_f64<0x142>(kd));
            kd = fmax(kd, dpp_f64<0x143>(kd));

            if ((t & 63) == 63)
                red[s & 1][t >> 6] = (unsigned long long)__double_as_longlong(kd);
            __syncthreads();

            double kc = __longlong_as_double((long long)red[s & 1][t & 7]);
            kc = fmax(kc, dpp_f64<0x111>(kc));
            kc = fmax(kc, dpp_f64<0x112>(kc));
            kc = fmax(kc, dpp_f64<0x114>(kc));

            const unsigned long long kw =
                (unsigned long long)__double_as_longlong(kc);
            const unsigned lo7 =
                (unsigned)__builtin_amdgcn_readlane((int)(unsigned)kw, 7);
            const int nxt = (int)(unsigned)(~lo7);

            px = xb[nxt * 3 + 0];
            py = xb[nxt * 3 + 1];
            pz = xb[nxt * 3 + 2];
        }
        return;
    }

    // ================= consumer: bq + mlp for group pairs =================
    const int h  = t >> 8;       // half 0 / half 1
    const int tt = t & 255;      // R8-style thread id within half
    const int cb = blockIdx.x - BATCH;

    // folded BN params (stable across pairs) — staged once by half 0
    if (t < 256) {
        if (tt < 64) {
            const float sv = g0[tt] * rsqrtf(v0[tt] + 1e-5f);
            sc[tt] = sv; bi[tt] = b0[tt] - m0[tt] * sv;
        } else if (tt < 128) {
            const int j = tt - 64;
            const float sv = g1[j] * rsqrtf(v1[j] + 1e-5f);
            sc[tt] = sv; bi[tt] = b1[j] - m1[j] * sv;
        } else {
            const int j = tt - 128;
            const float sv = g2[j] * rsqrtf(v2[j] + 1e-5f);
            sc[tt] = sv; bi[tt] = b2[j] - m2[j] * sv;
        }
    }

    for (int pair = cb; pair < NPAIR; pair += NCONS) {
        const int idx = pair * 2;        // s-major: idx = s*8 + b
        const int s   = idx >> 3;
        const int bA  = idx & 7;         // even; half 1 handles bA+1
        const int bh  = bA + h;

        if (t == 0) {
            while (__hip_atomic_load(&flags[bA * 32], __ATOMIC_ACQUIRE,
                                     __HIP_MEMORY_SCOPE_AGENT) <= (unsigned)s)
                __builtin_amdgcn_s_sleep(16);
            while (__hip_atomic_load(&flags[(bA + 1) * 32], __ATOMIC_ACQUIRE,
                                     __HIP_MEMORY_SCOPE_AGENT) <= (unsigned)s)
                __builtin_amdgcn_s_sleep(16);
        }
        __syncthreads();

        // --- bq: wave 0 of each half (R8 math) ---------------------------
        if (tt < 64) {
            const int lane = tt;
            const float* xb = xyz + (size_t)bh * NPT * 3;
            float qx = 0.f, qy = 0.f, qz = 0.f;
            if (lane == 0) {
                const unsigned* q =
                    (const unsigned*)(new_xyz + ((size_t)bh * NQ + s) * 3);
                qx = __uint_as_float(__hip_atomic_load(q + 0, __ATOMIC_RELAXED,
                                                       __HIP_MEMORY_SCOPE_AGENT));
                qy = __uint_as_float(__hip_atomic_load(q + 1, __ATOMIC_RELAXED,
                                                       __HIP_MEMORY_SCOPE_AGENT));
                qz = __uint_as_float(__hip_atomic_load(q + 2, __ATOMIC_RELAXED,
                                                       __HIP_MEMORY_SCOPE_AGENT));
                qbuf[h][0] = qx; qbuf[h][1] = qy; qbuf[h][2] = qz;
            }
            qx = __shfl(qx, 0, 64); qy = __shfl(qy, 0, 64); qz = __shfl(qz, 0, 64);

            int* outg = gidxL[h];
            const float R2 = 0.04f;   // f32(0.2*0.2 in f64)
            int cnt = 0, first = -1;
            for (int base = 0; base < NPT; base += 64) {
                const int p = base + lane;
                const float dx = __fsub_rn(xb[p * 3 + 0], qx);
                const float dy = __fsub_rn(xb[p * 3 + 1], qy);
                const float dz = __fsub_rn(xb[p * 3 + 2], qz);
                const float d  = __fadd_rn(__fadd_rn(__fmul_rn(dx, dx),
                                                     __fmul_rn(dy, dy)),
                                           __fmul_rn(dz, dz));
                const bool in = (d <= R2);
                const unsigned long long m = __ballot(in);
                if (first < 0 && m) first = base + (__ffsll((unsigned long long)m) - 1);
                if (in) {
                    const int pos = cnt + __popcll(m & ((1ull << lane) - 1ull));
                    if (pos < NS) outg[pos] = p;
                }
                cnt += __popcll(m);
                if (cnt >= NS) break;
            }
            if (cnt < NS) {
                const int f2 = (cnt > 0) ? first : (NPT - 1);
                for (int j = cnt + lane; j < NS; j += 64) outg[j] = f2;
            }
        }
        __syncthreads();

        // --- prefetch w1/w2 + stage w0 (half 0) --------------------------
        float4 r1[4], r2[8];
        if (t < 256) {
            const float4* s1 = (const float4*)(w1 + tt * 16);
#pragma unroll
            for (int q = 0; q < 4; ++q) r1[q] = s1[q];
            const float4* s2 = (const float4*)(w2 + tt * 32);
#pragma unroll
            for (int q = 0; q < 8; ++q) r2[q] = s2[q];

            for (int i = tt; i < 64 * 68; i += 256) {
                const int o = i / 68, c = i - o * 68;
                float v;
                if (c < 64)       v = w0[o * 67 + 3 + c];
                else if (c < 67)  v = w0[o * 67 + (c - 64)];
                else              v = 0.f;
                wbuf[i] = v;
            }
        }

        // --- gather into bufA[h] (both halves, R8 math) ------------------
        {
            const int k = tt >> 3, f = tt & 7;
            const int p = gidxL[h][k];
            const float* fr = feat + ((size_t)bh * NPT + p) * 64 + f * 8;
            const float4 a0 = *(const float4*)fr;
            const float4 a1 = *(const float4*)(fr + 4);
            float* bA_ = bufA[h];
            *(float4*)(bA_ + k * 68 + f * 8)     = a0;
            *(float4*)(bA_ + k * 68 + f * 8 + 4) = a1;
            if (f == 0) {
                const float* xp = xyz + ((size_t)bh * NPT + p) * 3;
                bA_[k * 68 + 64] = xp[0] - qbuf[h][0];
                bA_[k * 68 + 65] = xp[1] - qbuf[h][1];
                bA_[k * 68 + 66] = xp[2] - qbuf[h][2];
                bA_[k * 68 + 67] = 0.f;
            }
        }
        __syncthreads();

        mlp_layer<4>(bufA[h], wbuf, sc, bi, bufB[h], 17, tt);
        __syncthreads();

        if (t < 256) {
            float* dst = wbuf + (tt >> 2) * 68 + (tt & 3) * 16;
#pragma unroll
            for (int q = 0; q < 4; ++q) *(float4*)(dst + 4 * q) = r1[q];
        }
        __syncthreads();

        mlp_layer<4>(bufB[h], wbuf, sc + 64, bi + 64, bufA[h], 16, tt);
        __syncthreads();

        if (t < 256) {
            float* dst = wbuf + (tt >> 1) * 68 + (tt & 1) * 32;
#pragma unroll
            for (int q = 0; q < 8; ++q) *(float4*)(dst + 4 * q) = r2[q];
        }
        __syncthreads();

        mlp_layer2(bufA[h], wbuf, sc + 128, bi + 128, out, bh, s, tt);
        __syncthreads();   // wbuf/bufA reused next pair
    }
}

// ---------------------------------------------------------------------------
extern "C" void kernel_launch(void* const* d_in, const int* in_sizes, int n_in,
                              void* d_out, int out_size, void* d_ws, size_t ws_size,
                              hipStream_t stream)
{
    const float* xyz  = (const float*)d_in[0];
    const float* feat = (const float*)d_in[1];
    const float* w0 = (const float*)d_in[2];
    const float* g0 = (const float*)d_in[3];
    const float* b0 = (const float*)d_in[4];
    const float* m0 = (const float*)d_in[5];
    const float* v0 = (const float*)d_in[6];
    const float* w1 = (const float*)d_in[7];
    const float* g1 = (const float*)d_in[8];
    const float* b1 = (const float*)d_in[9];
    const float* m1 = (const float*)d_in[10];
    const float* v1 = (const float*)d_in[11];
    const float* w2 = (const float*)d_in[12];
    const float* g2 = (const float*)d_in[13];
    const float* b2 = (const float*)d_in[14];
    const float* m2 = (const float*)d_in[15];
    const float* v2 = (const float*)d_in[16];

    float* out      = (float*)d_out;
    float* new_xyz  = out;                      // 8*512*3 floats
    float* out_feat = out + BATCH * NQ * 3;     // 8*128*512 floats

    // progress flags: 8 batches x 1 u32, strided 128B to spread spin traffic
    unsigned* flags = (unsigned*)d_ws;
    (void)hipMemsetAsync(d_ws, 0, 1024, stream);

    fused_kernel<<<BATCH + NCONS, 512, 0, stream>>>(
        xyz, feat, new_xyz,
        w0, g0, b0, m0, v0,
        w1, g1, b1, m1, v1,
        w2, g2, b2, m2, v2,
        out_feat, flags);
}

// Round 16
// 1108.632 us; speedup vs baseline: 1.5333x; 1.5333x over previous
//
#include <hip/hip_runtime.h>
#include <hip/hip_bf16.h>

#define NPT   16384
#define NQ    512
#define NS    32
#define BATCH 8

typedef float f32x2 __attribute__((ext_vector_type(2)));

// ---------------------------------------------------------------------------
// DPP helper on a 64-bit value (two 32-bit halves), invalid lanes -> 0.
// 0 is the identity for our max since every real key > 0.
// Keys are (dist_bits<<32)|~idx with dist in [0,3] -> as f64 bit patterns they
// are positive, finite, never NaN; for positive doubles value order == bit
// order and CDNA never flushes f64 denormals, so v_max_f64 == exact u64 max.
// ---------------------------------------------------------------------------
template <int CTRL>
__device__ inline double dpp_f64(double x)
{
    const unsigned long long u = (unsigned long long)__double_as_longlong(x);
    int lo = (int)(unsigned)u;
    int hi = (int)(unsigned)(u >> 32);
    lo = __builtin_amdgcn_update_dpp(0, lo, CTRL, 0xf, 0xf, true);
    hi = __builtin_amdgcn_update_dpp(0, hi, CTRL, 0xf, 0xf, true);
    return __longlong_as_double(
        (long long)(((unsigned long long)(unsigned)hi << 32) | (unsigned)lo));
}

// ---------------------------------------------------------------------------
// Kernel 1: furthest point sampling — session-best R2 form (~791us).
// FINAL SESSION VERDICT (R0-R15): this is the practical floor.
//  - Single-block variants (regs/AGPR, LDS-resident, pk-asm, scalar,
//    launch-bounds/waves_per_eu knobs): 787-893us; issued VALU stream is
//    compiler-invariant at ~2x the minimal 13 instr/pt, + ~980cy/iter
//    serial reduce->fetch tail.
//  - Multi-block (FPB=4, per-iter device barrier, R11): 1471us — cross-XCD
//    atomic sync ~1.3us/iter > the ~1.0us/iter it parallelizes.
//  - Fused producer-consumer (R15): 1586us — per-iteration agent-scope
//    release stores + 248 consumers polling 8 flag lines stall the
//    producer ~2x; release semantics are NOT fire-and-forget at ISA level.
// 511 serial iterations on 8/256 CUs is the structural constraint.
// ---------------------------------------------------------------------------
__global__ __launch_bounds__(512)
__attribute__((amdgpu_waves_per_eu(2, 2)))
void fps_kernel(const float* __restrict__ xyz, float* __restrict__ new_xyz)
{
#pragma clang fp contract(off)
    const int b = blockIdx.x;
    const int t = threadIdx.x;
    const float* xb = xyz + (size_t)b * NPT * 3;

    f32x2 xr[16], yr[16], zr[16], dr[16];
    const float INF = __int_as_float(0x7f800000);
#pragma unroll
    for (int j = 0; j < 16; ++j) {
        const int p0 = (2 * j) * 512 + t;
        const int p1 = (2 * j + 1) * 512 + t;
        xr[j] = (f32x2){xb[p0 * 3 + 0], xb[p1 * 3 + 0]};
        yr[j] = (f32x2){xb[p0 * 3 + 1], xb[p1 * 3 + 1]};
        zr[j] = (f32x2){xb[p0 * 3 + 2], xb[p1 * 3 + 2]};
        dr[j] = (f32x2){INF, INF};
    }

    __shared__ unsigned long long red[2][8];

    float px = xb[0], py = xb[1], pz = xb[2];

    for (int s = 0; s < NQ; ++s) {
        if (t == 0) {
            float* o = new_xyz + ((size_t)b * NQ + s) * 3;
            o[0] = px; o[1] = py; o[2] = pz;
        }
        if (s == NQ - 1) break;

        // --- packed distance update + local argmax over 32 points ---------
        const f32x2 pxv = {px, px}, pyv = {py, py}, pzv = {pz, pz};
        float dmax = -1.0f;
        int   bi_  = 0;
#pragma unroll
        for (int j = 0; j < 16; ++j) {
            const f32x2 dx = xr[j] - pxv;
            const f32x2 dy = yr[j] - pyv;
            const f32x2 dz = zr[j] - pzv;
            f32x2 d = (dx * dx + dy * dy);       // rn mul/add, no fma
            d = d + dz * dz;
            const f32x2 dn = __builtin_elementwise_min(dr[j], d);
            dr[j] = dn;
            // within pair: .x has the smaller global index -> wins ties
            const float ds = (dn.x >= dn.y) ? dn.x : dn.y;
            const int   is = (dn.x >= dn.y) ? (2 * j) : (2 * j + 1);
            // across pairs ascending j: strict > keeps first occurrence
            if (ds > dmax) { dmax = ds; bi_ = is; }
        }

        const unsigned pidx = (unsigned)(bi_ * 512 + t);
        double kd = __longlong_as_double((long long)(
            ((unsigned long long)__float_as_uint(dmax) << 32) | (unsigned)(~pidx)));

        // --- wave max via DPP; lane 63 = wave max -------------------------
        kd = fmax(kd, dpp_f64<0x111>(kd));   // row_shr:1
        kd = fmax(kd, dpp_f64<0x112>(kd));   // row_shr:2
        kd = fmax(kd, dpp_f64<0x114>(kd));   // row_shr:4
        kd = fmax(kd, dpp_f64<0x118>(kd));   // row_shr:8
        kd = fmax(kd, dpp_f64<0x142>(kd));   // row_bcast:15
        kd = fmax(kd, dpp_f64<0x143>(kd));   // row_bcast:31

        if ((t & 63) == 63)
            red[s & 1][t >> 6] = (unsigned long long)__double_as_longlong(kd);
        __syncthreads();

        // --- cross-wave combine: slot = lane&7, 3 DPP stages --------------
        double kc = __longlong_as_double((long long)red[s & 1][t & 7]);
        kc = fmax(kc, dpp_f64<0x111>(kc));
        kc = fmax(kc, dpp_f64<0x112>(kc));
        kc = fmax(kc, dpp_f64<0x114>(kc));   // lane 7 of each row = global max

        const unsigned long long kw = (unsigned long long)__double_as_longlong(kc);
        const unsigned lo7 = (unsigned)__builtin_amdgcn_readlane((int)(unsigned)kw, 7);
        const int nxt = (int)(unsigned)(~lo7);   // uniform (SGPR)

        px = xb[nxt * 3 + 0];
        py = xb[nxt * 3 + 1];
        pz = xb[nxt * 3 + 2];
    }
}

// ---------------------------------------------------------------------------
// Kernel 2: ball query. One wave per (b,s) query; ascending index scan with
// ballot + prefix popcount collects exactly the 32 smallest in-radius indices.
// ---------------------------------------------------------------------------
__global__ __launch_bounds__(256) void bq_kernel(const float* __restrict__ xyz,
                                                 const float* __restrict__ newxyz,
                                                 int* __restrict__ gidx)
{
    const int wid  = (blockIdx.x * 256 + threadIdx.x) >> 6;  // 0..4095
    const int lane = threadIdx.x & 63;
    const int b    = wid >> 9;
    const float* xb = xyz + (size_t)b * NPT * 3;

    const float qx = newxyz[wid * 3 + 0];
    const float qy = newxyz[wid * 3 + 1];
    const float qz = newxyz[wid * 3 + 2];
    int* out = gidx + (size_t)wid * NS;

    const float R2 = 0.04f;   // f32(0.2*0.2 in f64); NOT 0.2f*0.2f (1 ulp higher)
    int cnt = 0, first = -1;

    for (int base = 0; base < NPT; base += 64) {
        const int p = base + lane;
        const float dx = __fsub_rn(xb[p * 3 + 0], qx);
        const float dy = __fsub_rn(xb[p * 3 + 1], qy);
        const float dz = __fsub_rn(xb[p * 3 + 2], qz);
        const float d  = __fadd_rn(__fadd_rn(__fmul_rn(dx, dx), __fmul_rn(dy, dy)),
                                   __fmul_rn(dz, dz));
        const bool in = (d <= R2);
        const unsigned long long m = __ballot(in);
        if (first < 0 && m) first = base + (__ffsll((unsigned long long)m) - 1);
        if (in) {
            const int pos = cnt + __popcll(m & ((1ull << lane) - 1ull));
            if (pos < NS) out[pos] = p;
        }
        cnt += __popcll(m);
        if (cnt >= NS) break;
    }
    if (cnt < NS) {
        const int f = (cnt > 0) ? first : (NPT - 1);
        for (int j = cnt + lane; j < NS; j += 64) out[j] = f;
    }
}

// ---------------------------------------------------------------------------
// Kernel 3: gather + 3-layer MLP (BN folded) + max over the 32 samples.
// One block per (b,s). EXACT R8 version (best measured: total 1107.1us).
// w1/w2 prefetched to registers at entry (T14, +20us vs serial staging),
// drained after the barriers that free wbuf. Pad cols never read by l1/l2.
// R9/R10's l2-split + gather-hoist bundle regressed ~125us -> reverted.
// ---------------------------------------------------------------------------
template <int OP>
__device__ inline void mlp_layer(const float* __restrict__ inb,
                                 const float* __restrict__ wbuf,
                                 const float* __restrict__ scp,
                                 const float* __restrict__ bip,
                                 float* __restrict__ outb, int nchunk, int t)
{
    const int ko = t & 15;
    const int og = t >> 4;
    const int o0 = og * OP;
    float acc0[OP], acc1[OP];
#pragma unroll
    for (int j = 0; j < OP; ++j) { acc0[j] = 0.f; acc1[j] = 0.f; }

    for (int cc = 0; cc < nchunk; ++cc) {
        const int c = cc * 4;
        const float4 xa = *(const float4*)(inb + ko * 68 + c);
        const float4 xb = *(const float4*)(inb + (ko + 16) * 68 + c);
#pragma unroll
        for (int j = 0; j < OP; ++j) {
            const float4 w = *(const float4*)(wbuf + (o0 + j) * 68 + c);
            acc0[j] += xa.x * w.x + xa.y * w.y + xa.z * w.z + xa.w * w.w;
            acc1[j] += xb.x * w.x + xb.y * w.y + xb.z * w.z + xb.w * w.w;
        }
    }
#pragma unroll
    for (int j = 0; j < OP; ++j) {
        const float sv = scp[o0 + j], bv = bip[o0 + j];
        acc0[j] = fmaxf(acc0[j] * sv + bv, 0.f);
        acc1[j] = fmaxf(acc1[j] * sv + bv, 0.f);
    }
#pragma unroll
    for (int jb = 0; jb < OP; jb += 4) {
        *(float4*)(outb + ko * 68 + o0 + jb) =
            make_float4(acc0[jb], acc0[jb + 1], acc0[jb + 2], acc0[jb + 3]);
        *(float4*)(outb + (ko + 16) * 68 + o0 + jb) =
            make_float4(acc1[jb], acc1[jb + 1], acc1[jb + 2], acc1[jb + 3]);
    }
}

__device__ inline void mlp_layer2(const float* __restrict__ inb,
                                  const float* __restrict__ wbuf,
                                  const float* __restrict__ scp,
                                  const float* __restrict__ bip,
                                  float* __restrict__ out, int b, int s, int t)
{
    const int ko = t & 15;
    const int og = t >> 4;
    const int o0 = og * 8;
    float acc0[8], acc1[8];
#pragma unroll
    for (int j = 0; j < 8; ++j) { acc0[j] = 0.f; acc1[j] = 0.f; }

    for (int cc = 0; cc < 16; ++cc) {
        const int c = cc * 4;
        const float4 xa = *(const float4*)(inb + ko * 68 + c);
        const float4 xb = *(const float4*)(inb + (ko + 16) * 68 + c);
#pragma unroll
        for (int j = 0; j < 8; ++j) {
            const float4 w = *(const float4*)(wbuf + (o0 + j) * 68 + c);
            acc0[j] += xa.x * w.x + xa.y * w.y + xa.z * w.z + xa.w * w.w;
            acc1[j] += xb.x * w.x + xb.y * w.y + xb.z * w.z + xb.w * w.w;
        }
    }
    float v[8];
#pragma unroll
    for (int j = 0; j < 8; ++j) {
        const float sv = scp[o0 + j], bv = bip[o0 + j];
        const float h0 = fmaxf(acc0[j] * sv + bv, 0.f);
        const float h1 = fmaxf(acc1[j] * sv + bv, 0.f);
        v[j] = fmaxf(h0, h1);
    }
#pragma unroll
    for (int m = 1; m <= 8; m <<= 1) {
#pragma unroll
        for (int j = 0; j < 8; ++j) v[j] = fmaxf(v[j], __shfl_xor(v[j], m, 64));
    }
    if (ko == 0) {
#pragma unroll
        for (int j = 0; j < 8; ++j)
            out[((size_t)b * 128 + o0 + j) * NQ + s] = v[j];
    }
}

__global__ __launch_bounds__(256) void mlp_kernel(
    const float* __restrict__ xyz, const float* __restrict__ feat,
    const float* __restrict__ newxyz, const int* __restrict__ gidx,
    const float* __restrict__ w0, const float* __restrict__ g0,
    const float* __restrict__ b0, const float* __restrict__ m0,
    const float* __restrict__ v0,
    const float* __restrict__ w1, const float* __restrict__ g1,
    const float* __restrict__ b1, const float* __restrict__ m1,
    const float* __restrict__ v1,
    const float* __restrict__ w2, const float* __restrict__ g2,
    const float* __restrict__ b2, const float* __restrict__ m2,
    const float* __restrict__ v2,
    float* __restrict__ out)
{
    __shared__ float wbuf[128 * 68];   // 34816 B
    __shared__ float bufA[32 * 68];    //  8704 B
    __shared__ float bufB[32 * 68];    //  8704 B
    __shared__ float sc[256], bi[256]; //  2048 B   -> total 54272 B

    const int t   = threadIdx.x;
    const int grp = blockIdx.x;       // 0..4095
    const int b   = grp >> 9;
    const int s   = grp & (NQ - 1);
    const int* gi = gidx + (size_t)grp * NS;

    // T14: issue w1/w2 loads NOW; latency hides under BN + w0 staging + l0.
    float4 r1[4], r2[8];
    {
        const float4* s1 = (const float4*)(w1 + t * 16);
#pragma unroll
        for (int q = 0; q < 4; ++q) r1[q] = s1[q];
        const float4* s2 = (const float4*)(w2 + t * 32);
#pragma unroll
        for (int q = 0; q < 8; ++q) r2[q] = s2[q];
    }

    // folded BN params for all three layers
    if (t < 64) {
        const float sv = g0[t] * rsqrtf(v0[t] + 1e-5f);
        sc[t] = sv; bi[t] = b0[t] - m0[t] * sv;
    } else if (t < 128) {
        const int j = t - 64;
        const float sv = g1[j] * rsqrtf(v1[j] + 1e-5f);
        sc[t] = sv; bi[t] = b1[j] - m1[j] * sv;
    } else {
        const int j = t - 128;
        const float sv = g2[j] * rsqrtf(v2[j] + 1e-5f);
        sc[t] = sv; bi[t] = b2[j] - m2[j] * sv;
    }

    // layer-0 weights, channel-permuted: [feat 0..63 | xyz 64..66 | 0]
    for (int i = t; i < 64 * 68; i += 256) {
        const int o = i / 68, c = i - o * 68;
        float v;
        if (c < 64)       v = w0[o * 67 + 3 + c];
        else if (c < 67)  v = w0[o * 67 + (c - 64)];
        else              v = 0.f;
        wbuf[i] = v;
    }

    // gather x into bufA: feat then xyz-diff
    {
        const int k = t >> 3, f = t & 7;
        const int p = gi[k];
        const float* fr = feat + ((size_t)b * NPT + p) * 64 + f * 8;
        const float4 a0 = *(const float4*)fr;
        const float4 a1 = *(const float4*)(fr + 4);
        *(float4*)(bufA + k * 68 + f * 8)     = a0;
        *(float4*)(bufA + k * 68 + f * 8 + 4) = a1;
        if (f == 0) {
            const float qx = newxyz[grp * 3 + 0];
            const float qy = newxyz[grp * 3 + 1];
            const float qz = newxyz[grp * 3 + 2];
            const float* xp = xyz + ((size_t)b * NPT + p) * 3;
            bufA[k * 68 + 64] = xp[0] - qx;
            bufA[k * 68 + 65] = xp[1] - qy;
            bufA[k * 68 + 66] = xp[2] - qz;
            bufA[k * 68 + 67] = 0.f;
        }
    }
    __syncthreads();

    mlp_layer<4>(bufA, wbuf, sc, bi, bufB, 17, t);
    __syncthreads();

    // drain prefetched w1 into wbuf (pads c>=64 never read by l1)
    {
        float* dst = wbuf + (t >> 2) * 68 + (t & 3) * 16;
#pragma unroll
        for (int q = 0; q < 4; ++q) *(float4*)(dst + 4 * q) = r1[q];
    }
    __syncthreads();

    mlp_layer<4>(bufB, wbuf, sc + 64, bi + 64, bufA, 16, t);
    __syncthreads();

    // drain prefetched w2 into wbuf (pads c>=64 never read by l2)
    {
        float* dst = wbuf + (t >> 1) * 68 + (t & 1) * 32;
#pragma unroll
        for (int q = 0; q < 8; ++q) *(float4*)(dst + 4 * q) = r2[q];
    }
    __syncthreads();

    mlp_layer2(bufA, wbuf, sc + 128, bi + 128, out, b, s, t);
}

// ---------------------------------------------------------------------------
extern "C" void kernel_launch(void* const* d_in, const int* in_sizes, int n_in,
                              void* d_out, int out_size, void* d_ws, size_t ws_size,
                              hipStream_t stream)
{
    const float* xyz  = (const float*)d_in[0];
    const float* feat = (const float*)d_in[1];
    const float* w0 = (const float*)d_in[2];
    const float* g0 = (const float*)d_in[3];
    const float* b0 = (const float*)d_in[4];
    const float* m0 = (const float*)d_in[5];
    const float* v0 = (const float*)d_in[6];
    const float* w1 = (const float*)d_in[7];
    const float* g1 = (const float*)d_in[8];
    const float* b1 = (const float*)d_in[9];
    const float* m1 = (const float*)d_in[10];
    const float* v1 = (const float*)d_in[11];
    const float* w2 = (const float*)d_in[12];
    const float* g2 = (const float*)d_in[13];
    const float* b2 = (const float*)d_in[14];
    const float* m2 = (const float*)d_in[15];
    const float* v2 = (const float*)d_in[16];

    float* out      = (float*)d_out;
    float* new_xyz  = out;                      // 8*512*3 = 12288 floats
    float* out_feat = out + BATCH * NQ * 3;     // 8*128*512 floats
    int*   gidx     = (int*)d_ws;               // 4096*32 ints = 512 KB

    fps_kernel<<<BATCH, 512, 0, stream>>>(xyz, new_xyz);
    bq_kernel<<<(BATCH * NQ * 64) / 256, 256, 0, stream>>>(xyz, new_xyz, gidx);
    mlp_kernel<<<BATCH * NQ, 256, 0, stream>>>(xyz, feat, new_xyz, gidx,
                                               w0, g0, b0, m0, v0,
                                               w1, g1, b1, m1, v1,
                                               w2, g2, b2, m2, v2,
                                               out_feat);
}